// Round 4
// baseline (975.161 us; speedup 1.0000x reference)
//
#include <hip/hip_runtime.h>
#include <math.h>

typedef _Float16 f16x8 __attribute__((ext_vector_type(8)));
typedef _Float16 f16x4 __attribute__((ext_vector_type(4)));
typedef float    f32x16 __attribute__((ext_vector_type(16)));

#define NTT 27
#define FVS 384          // fv LDS row stride in f16 (768 B)
#define O1S 320          // o1 LDS row stride in f16 (640 B)
#define W1F_ELEMS 86016  // 8 nb * 21 kc * 2 lq * 32 lr * 8
#define W2F_ELEMS 34816  // 4 mb * 17 kc * 2 lq * 32 lr * 8

__device__ __forceinline__ void f16split(float x, _Float16& h, _Float16& l) {
    h = (_Float16)x;
    l = (_Float16)((x - (float)h) * 2048.0f);   // scaled-lo: stays in normal range
}

// ---- prep: split weights into MFMA-fragment-ordered hi/lo planes ----------
// W1F[nb][kc][lq][lr][e]: n = nb*32+lr, k = kc*16+lq*8+e  (k=324 -> bias, pad 0)
// W2F[mb][kc][lq][lr][e]: m = mb*32+lr, k = kc*16+lq*8+e  (k=256 -> bias, pad 0)
__global__ __launch_bounds__(256) void prep_weights(
    const float* __restrict__ W1, const float* __restrict__ b1,
    const float* __restrict__ W2, const float* __restrict__ b2,
    _Float16* __restrict__ W1Fh, _Float16* __restrict__ W1Fl,
    _Float16* __restrict__ W2Fh, _Float16* __restrict__ W2Fl)
{
    int i = blockIdx.x * 256 + threadIdx.x;
    if (i < W1F_ELEMS) {
        int e  = i & 7, lr = (i >> 3) & 31, lq = (i >> 8) & 1;
        int j3 = i >> 9;                 // nb*21 + kc
        int nb = j3 / 21, kc = j3 - nb * 21;
        int n = nb * 32 + lr, k = kc * 16 + lq * 8 + e;
        float x = (k < 324) ? W1[k * 256 + n] : ((k == 324) ? b1[n] : 0.f);
        _Float16 h, l; f16split(x, h, l);
        W1Fh[i] = h; W1Fl[i] = l;
    } else {
        int j = i - W1F_ELEMS;
        if (j < W2F_ELEMS) {
            int e  = j & 7, lr = (j >> 3) & 31, lq = (j >> 8) & 1;
            int j3 = j >> 9;             // mb*17 + kc
            int mb = j3 / 17, kc = j3 - mb * 17;
            int m = mb * 32 + lr, k = kc * 16 + lq * 8 + e;
            float x = (k < 256) ? W2[k * 128 + m] : ((k == 256) ? b2[m] : 0.f);
            _Float16 h, l; f16split(x, h, l);
            W2Fh[j] = h; W2Fl[j] = l;
        }
    }
}

// ---- encoder1: gather -> split-f16 MFMA GEMM1(relu) -> GEMM2 -> h2 --------
// h2 layout: [b][m][a][c] (channel-major for pooling)
__global__ __launch_bounds__(256) void encoder1_kernel(
    const float* __restrict__ f0, const float* __restrict__ f1,
    const float* __restrict__ f2, const float* __restrict__ f3,
    const _Float16* __restrict__ W1Fh, const _Float16* __restrict__ W1Fl,
    const _Float16* __restrict__ W2Fh, const _Float16* __restrict__ W2Fl,
    float* __restrict__ h2)
{
    // 49152 B LDS -> 3 blocks/CU. fv planes [32][384]; o1 planes [32][320] alias.
    __shared__ _Float16 smem[24576];
    _Float16* fvh = smem;
    _Float16* fvl = smem + 12288;
    _Float16* o1h = smem;            // alias (behind barrier)
    _Float16* o1l = smem + 10240;

    const int tid = threadIdx.x;
    const int bid = blockIdx.x;
    const int b   = bid >> 9;
    const int rem = bid & 511;
    const int a   = rem >> 2;
    const int c0  = (rem & 3) * 32;

    // ---- gather fv tile [32 r][324 k] as float4, split to f16 hi/lo planes
    {
        const int base_bt = ((b * NTT) * 128 + a) * 384 + c0 * 3;
        for (int idx = tid; idx < NTT * 4 * 24; idx += 256) {
            int seg = idx / 24;             // t*4 + src
            int q   = idx - seg * 24;       // float4 within 96-float segment
            int t   = seg >> 2, src = seg & 3;
            const float* sp = (src == 0) ? f0 : (src == 1) ? f1 : (src == 2) ? f2 : f3;
            float4 v = *(const float4*)(sp + base_bt + t * 49152 + q * 4);
            float vv[4] = {v.x, v.y, v.z, v.w};
            #pragma unroll
            for (int e = 0; e < 4; ++e) {
                int f = q * 4 + e;          // = r*3 + comp
                int r = f / 3, comp = f - r * 3;
                int col = t * 12 + src * 3 + comp;
                int u = (r * FVS + col) ^ ((r & 7) << 3);
                _Float16 h, l; f16split(vv[e], h, l);
                fvh[u] = h; fvl[u] = l;
            }
        }
        // bias column (k=324 -> 1.0) + zero pad k=325..335
        for (int i = tid; i < 32 * 12; i += 256) {
            int r = i / 12, col = 324 + (i - (i / 12) * 12);
            int u = (r * FVS + col) ^ ((r & 7) << 3);
            fvh[u] = (col == 324) ? (_Float16)1.0f : (_Float16)0.0f;
            fvl[u] = (_Float16)0.0f;
        }
    }
    __syncthreads();

    const int lane = tid & 63;
    const int w    = tid >> 6;        // wave id 0..3
    const int lr   = lane & 31;       // A-row / B-col index
    const int lq   = lane >> 5;       // k-group
    const int swz  = (lr & 7) << 3;   // 16B-granular XOR swizzle (f16 units)

    // ---- GEMM1: O1T[256 n][32 r] = W1T x fvT, 6 independent MFMA chains
    f32x16 accm[2], accxa[2], accxb[2];
    #pragma unroll
    for (int e = 0; e < 16; ++e) {
        accm[0][e] = 0.f; accm[1][e] = 0.f;
        accxa[0][e] = 0.f; accxa[1][e] = 0.f;
        accxb[0][e] = 0.f; accxb[1][e] = 0.f;
    }
    const int fvrow = lr * FVS;
    // fragment-ordered base offsets: addr = base_t + kc*512
    const int wb0 = ((w * 2 + 0) * 42 + lq) * 256 + lr * 8;
    const int wb1 = ((w * 2 + 1) * 42 + lq) * 256 + lr * 8;
    #pragma unroll 3
    for (int kc = 0; kc < 21; ++kc) {
        const int col = kc * 16 + lq * 8;
        f16x8 bh = *(const f16x8*)&fvh[(fvrow + col) ^ swz];
        f16x8 bl = *(const f16x8*)&fvl[(fvrow + col) ^ swz];
        const int o0 = wb0 + kc * 512, o1 = wb1 + kc * 512;
        f16x8 ah0 = *(const f16x8*)(W1Fh + o0);
        f16x8 al0 = *(const f16x8*)(W1Fl + o0);
        f16x8 ah1 = *(const f16x8*)(W1Fh + o1);
        f16x8 al1 = *(const f16x8*)(W1Fl + o1);
        accm[0]  = __builtin_amdgcn_mfma_f32_32x32x16_f16(ah0, bh, accm[0], 0, 0, 0);
        accxa[0] = __builtin_amdgcn_mfma_f32_32x32x16_f16(ah0, bl, accxa[0], 0, 0, 0);
        accxb[0] = __builtin_amdgcn_mfma_f32_32x32x16_f16(al0, bh, accxb[0], 0, 0, 0);
        accm[1]  = __builtin_amdgcn_mfma_f32_32x32x16_f16(ah1, bh, accm[1], 0, 0, 0);
        accxa[1] = __builtin_amdgcn_mfma_f32_32x32x16_f16(ah1, bl, accxa[1], 0, 0, 0);
        accxb[1] = __builtin_amdgcn_mfma_f32_32x32x16_f16(al1, bh, accxb[1], 0, 0, 0);
    }
    __syncthreads();   // all fv reads done; o1 planes alias fv region

    // ---- epilogue 1: combine, relu, split -> o1 planes (8B f16x4 stores)
    const int o1row = lr * O1S;
    #pragma unroll
    for (int t = 0; t < 2; ++t) {
        #pragma unroll
        for (int g = 0; g < 4; ++g) {
            const int n0 = (w * 2 + t) * 32 + g * 8 + lq * 4;
            f16x4 ph, pl;
            #pragma unroll
            for (int e = 0; e < 4; ++e) {
                float v = accm[t][g * 4 + e]
                        + (accxa[t][g * 4 + e] + accxb[t][g * 4 + e]) * 4.8828125e-4f;
                v = fmaxf(v, 0.f);
                _Float16 h, l; f16split(v, h, l);
                ph[e] = h; pl[e] = l;
            }
            int u = (o1row + n0) ^ swz;
            *(f16x4*)&o1h[u] = ph;
            *(f16x4*)&o1l[u] = pl;
        }
    }
    // bias column (k=256 -> 1.0) + zero pad k=257..271
    for (int i = tid; i < 32 * 16; i += 256) {
        int r = i >> 4, col = 256 + (i & 15);
        int u = (r * O1S + col) ^ ((r & 7) << 3);
        o1h[u] = (col == 256) ? (_Float16)1.0f : (_Float16)0.0f;
        o1l[u] = (_Float16)0.0f;
    }
    __syncthreads();

    // ---- GEMM2: O2T[128 m][32 r] = W2T x O1T, 3 independent chains
    f32x16 cm, cxa, cxb;
    #pragma unroll
    for (int e = 0; e < 16; ++e) { cm[e] = 0.f; cxa[e] = 0.f; cxb[e] = 0.f; }
    const int wb2 = (w * 34 + lq) * 256 + lr * 8;
    #pragma unroll 3
    for (int kc = 0; kc < 17; ++kc) {
        const int col = kc * 16 + lq * 8;
        f16x8 bh = *(const f16x8*)&o1h[(o1row + col) ^ swz];
        f16x8 bl = *(const f16x8*)&o1l[(o1row + col) ^ swz];
        const int o2 = wb2 + kc * 512;
        f16x8 ah = *(const f16x8*)(W2Fh + o2);
        f16x8 al = *(const f16x8*)(W2Fl + o2);
        cm  = __builtin_amdgcn_mfma_f32_32x32x16_f16(ah, bh, cm, 0, 0, 0);
        cxa = __builtin_amdgcn_mfma_f32_32x32x16_f16(ah, bl, cxa, 0, 0, 0);
        cxb = __builtin_amdgcn_mfma_f32_32x32x16_f16(al, bh, cxb, 0, 0, 0);
    }

    // ---- direct coalesced store: h2[b][m][a][c0+lr]
    {
        float* op = h2 + (size_t)b * 2097152 + (size_t)a * 128 + c0 + lr;
        #pragma unroll
        for (int reg = 0; reg < 16; ++reg) {
            int m = w * 32 + (reg & 3) + (reg >> 2) * 8 + lq * 4;
            op[(size_t)m * 16384] = cm[reg] + (cxa[reg] + cxb[reg]) * 4.8828125e-4f;
        }
    }
}

// -------------------- pooling: 8 invariants per (b, m) ---------------------
__global__ __launch_bounds__(256) void pool_kernel(const float* __restrict__ h2,
                                                   float* __restrict__ feat)
{
    __shared__ float xs[16384];   // 64 KB, swizzled: (a,c) at xs[a*128 + (c ^ (a&31))]
    const int tid = threadIdx.x;
    const int bm = blockIdx.x;    // b*128 + m
    const float* x = h2 + (size_t)bm * 16384;

    float s1 = 0.f, s4 = 0.f;
    for (int i = tid; i < 16384; i += 256) {
        float v = x[i];
        int aa = i >> 7, cc = i & 127;
        xs[aa * 128 + (cc ^ (aa & 31))] = v;
        s1 += v;
        s4 = fmaf(v, v, s4);
    }
    __syncthreads();

    const int i2 = tid >> 1, hh = tid & 1;   // pair (2i,2i+1) handles index i
    float rp = 0.f;
    #pragma unroll 4
    for (int j = 0; j < 64; ++j) {
        int cc = hh * 64 + j;
        rp += xs[i2 * 128 + (cc ^ (i2 & 31))];
    }
    float rowv = rp + __shfl_xor(rp, 1, 64);

    float cp = 0.f;
    #pragma unroll 4
    for (int j = 0; j < 64; ++j) {
        int aa = hh * 64 + j;
        cp += xs[aa * 128 + (i2 ^ (aa & 31))];
    }
    float colv = cp + __shfl_xor(cp, 1, 64);

    float d = xs[i2 * 128 + (i2 ^ (i2 & 31))];

    float s5 = 0.f;
    for (int i = tid; i < 16384; i += 256) {
        int aa = i >> 7, cc = i & 127;
        float v1 = xs[aa * 128 + (cc ^ (aa & 31))];
        float v2 = xs[cc * 128 + (aa ^ (cc & 31))];
        s5 = fmaf(v1, v2, s5);
    }

    float s[8];
    s[0] = d * 0.5f;            // each index held by 2 threads -> halve
    s[1] = s1;
    s[2] = d * d * 0.5f;
    s[3] = d * rowv * 0.5f;
    s[4] = s4;
    s[5] = s5;
    s[6] = rowv * rowv * 0.5f;
    s[7] = rowv * colv * 0.5f;

    __syncthreads();            // done reading xs; reuse as reduction scratch
    #pragma unroll
    for (int off = 32; off > 0; off >>= 1)
        #pragma unroll
        for (int q = 0; q < 8; ++q) s[q] += __shfl_down(s[q], off, 64);

    const int wid = tid >> 6;
    if ((tid & 63) == 0) {
        #pragma unroll
        for (int q = 0; q < 8; ++q) xs[wid * 8 + q] = s[q];
    }
    __syncthreads();
    if (tid == 0) {
        const float den[8] = {128.f, 16384.f, 128.f, 16384.f,
                              16384.f, 16384.f, 2097152.f, 2097152.f};
        const int b = bm >> 7, m = bm & 127;
        #pragma unroll
        for (int q = 0; q < 8; ++q) {
            float v = (xs[q] + xs[8 + q] + xs[16 + q] + xs[24 + q]) / den[q];
            float vl = copysignf(log1pf(fabsf(v)), v) * 0.1f;
            feat[b * 1024 + q * 128 + m] = vl;
        }
    }
}

// -------------------- head: relu(feat@W3+b3)@W4+b4, tanh*8 -----------------
__global__ __launch_bounds__(256) void head_kernel(
    const float* __restrict__ feat, const float* __restrict__ W3,
    const float* __restrict__ b3, const float* __restrict__ W4,
    const float* __restrict__ b4, float* __restrict__ out)
{
    __shared__ float fs[1024];
    __shared__ float red[8];
    const int tid = threadIdx.x, b = blockIdx.x;
    for (int i = tid; i < 1024; i += 256) fs[i] = feat[b * 1024 + i];
    __syncthreads();
    float acc = b3[tid];
    #pragma unroll 8
    for (int k = 0; k < 1024; ++k) acc = fmaf(fs[k], W3[k * 256 + tid], acc);
    float g = fmaxf(acc, 0.f);
    float p0 = g * W4[tid * 2 + 0];
    float p1 = g * W4[tid * 2 + 1];
    #pragma unroll
    for (int off = 32; off > 0; off >>= 1) {
        p0 += __shfl_down(p0, off, 64);
        p1 += __shfl_down(p1, off, 64);
    }
    const int wid = tid >> 6;
    if ((tid & 63) == 0) { red[wid * 2] = p0; red[wid * 2 + 1] = p1; }
    __syncthreads();
    if (tid == 0) {
        float o0 = red[0] + red[2] + red[4] + red[6] + b4[0];
        float o1 = red[1] + red[3] + red[5] + red[7] + b4[1];
        out[b * 2 + 0] = tanhf(o0) * 8.f;
        out[b * 2 + 1] = tanhf(o1) * 8.f;
    }
}

extern "C" void kernel_launch(void* const* d_in, const int* in_sizes, int n_in,
                              void* d_out, int out_size, void* d_ws, size_t ws_size,
                              hipStream_t stream)
{
    const float* f0 = (const float*)d_in[0];
    const float* f1 = (const float*)d_in[1];
    const float* f2 = (const float*)d_in[2];
    const float* f3 = (const float*)d_in[3];
    const float* W1 = (const float*)d_in[4];
    const float* b1 = (const float*)d_in[5];
    const float* W2 = (const float*)d_in[6];
    const float* b2 = (const float*)d_in[7];
    const float* W3 = (const float*)d_in[8];
    const float* b3 = (const float*)d_in[9];
    const float* W4 = (const float*)d_in[10];
    const float* b4 = (const float*)d_in[11];

    float* h2   = (float*)d_ws;                       // 16*128*128*128 f32 = 128 MiB
    float* feat = h2 + (size_t)33554432;              // 16*1024 f32
    _Float16* W1Fh = (_Float16*)(feat + 16384);
    _Float16* W1Fl = W1Fh + W1F_ELEMS;
    _Float16* W2Fh = W1Fl + W1F_ELEMS;
    _Float16* W2Fl = W2Fh + W2F_ELEMS;

    prep_weights<<<472, 256, 0, stream>>>(W1, b1, W2, b2, W1Fh, W1Fl, W2Fh, W2Fl);
    encoder1_kernel<<<16 * 128 * 4, 256, 0, stream>>>(f0, f1, f2, f3,
                                                      W1Fh, W1Fl, W2Fh, W2Fl, h2);
    pool_kernel<<<16 * 128, 256, 0, stream>>>(h2, feat);
    head_kernel<<<16, 256, 0, stream>>>(feat, W3, b3, W4, b4, (float*)d_out);
}